// Round 2
// baseline (749.487 us; speedup 1.0000x reference)
//
#include <hip/hip_runtime.h>
#include <stdint.h>

typedef unsigned short u16;
typedef __bf16 bf16x8 __attribute__((ext_vector_type(8)));
typedef float  f32x4  __attribute__((ext_vector_type(4)));
typedef float  f32x2  __attribute__((ext_vector_type(2)));

#define GLOBAL_AS __attribute__((address_space(1)))
#define LDS_AS    __attribute__((address_space(3)))

#define B_ 4
#define L_ 4096
#define D_ 1024
#define H_ 16
#define TD 3072         // 3*D
#define NCHUNK 16
#define TCHUNK 256      // L_/NCHUNK

__device__ __forceinline__ float bf2f(u16 h) {
    union { uint32_t u; float f; } v; v.u = ((uint32_t)h) << 16; return v.f;
}
// unpack one u32 (2 packed bf16) -> f32x2 {lo, hi}; 2 VALU ops (lshl, and)
__device__ __forceinline__ f32x2 bf2x2(uint32_t u) {
    union { uint32_t u; float f; } lo, hi;
    lo.u = u << 16; hi.u = u & 0xffff0000u;
    f32x2 r; r.x = lo.f; r.y = hi.f; return r;
}
__device__ __forceinline__ u16 f2bf(float f) {
    union { float f; uint32_t u; } v; v.f = f;
    uint32_t u = v.u;
    u += 0x7fffu + ((u >> 16) & 1u);   // round-to-nearest-even
    return (u16)(u >> 16);
}

// pack 8 contiguous fp32 into 8 bf16 (RTE)
__device__ __forceinline__ uint4 ld8f(const float* p) {
    const float4 a = *(const float4*)p;
    const float4 b = *(const float4*)(p + 4);
    uint4 r;
    r.x = (uint32_t)f2bf(a.x) | ((uint32_t)f2bf(a.y) << 16);
    r.y = (uint32_t)f2bf(a.z) | ((uint32_t)f2bf(a.w) << 16);
    r.z = (uint32_t)f2bf(b.x) | ((uint32_t)f2bf(b.y) << 16);
    r.w = (uint32_t)f2bf(b.z) | ((uint32_t)f2bf(b.w) << 16);
    return r;
}

// store helper: C is bf16 (qkv intermediate) or fp32 (final output)
__device__ __forceinline__ void stc(u16* p, float v)   { *p = f2bf(v); }
__device__ __forceinline__ void stc(float* p, float v) { *p = v; }

// fp32 -> bf16 bulk convert, 8 elems/thread
__global__ __launch_bounds__(256) void cvt_f32_bf16(
    const float* __restrict__ in, u16* __restrict__ out, size_t n8)
{
    size_t i = (size_t)blockIdx.x * 256 + threadIdx.x;
    if (i >= n8) return;
    *(uint4*)(out + i * 8) = ld8f(in + i * 8);
}

// ---------------------------------------------------------------------------
// NT GEMM (m97 structure): C(M,N) = A(M,K)bf16 @ W(N,K)bf16^T + bias(fp32).
// 128x128 tile, BK=32, 256 thr (4 waves), 4x4 16x16x32 MFMA per wave.
// Staging via global_load_lds width=16 into LINEAR LDS [128][32].
// ---------------------------------------------------------------------------
template <typename TC>
__global__ __launch_bounds__(256) void gemm_bt_bias_bf16(
    const u16* __restrict__ A, const u16* __restrict__ W,
    const float* __restrict__ bias, TC* __restrict__ C,
    int M, int N, int K)
{
    __shared__ u16 As[128 * 32];
    __shared__ u16 Bs[128 * 32];

    const int tid  = threadIdx.x;
    const int lane = tid & 63;
    const int wid  = tid >> 6;
    const int bm = blockIdx.y * 128;
    const int bn = blockIdx.x * 128;

    const int wm = (wid & 1) * 64;
    const int wn = (wid >> 1) * 64;
    const int fr   = lane & 15;
    const int quad = lane >> 4;

    const u16* Ag = A + (size_t)(bm + (tid >> 2)) * K + (tid & 3) * 8;
    const u16* Wg = W + (size_t)(bn + (tid >> 2)) * K + (tid & 3) * 8;
    const size_t rskip = (size_t)64 * K;

    u16* AsW = As + wid * 512;      // wave-uniform LDS base, round 0
    u16* BsW = Bs + wid * 512;

    f32x4 acc[4][4] = {};

    for (int k0 = 0; k0 < K; k0 += 32) {
        __syncthreads();            // all waves done reading previous tile
        __builtin_amdgcn_global_load_lds((const GLOBAL_AS void*)(Ag + k0),
                                         (LDS_AS void*)(AsW),        16, 0, 0);
        __builtin_amdgcn_global_load_lds((const GLOBAL_AS void*)(Ag + rskip + k0),
                                         (LDS_AS void*)(AsW + 2048), 16, 0, 0);
        __builtin_amdgcn_global_load_lds((const GLOBAL_AS void*)(Wg + k0),
                                         (LDS_AS void*)(BsW),        16, 0, 0);
        __builtin_amdgcn_global_load_lds((const GLOBAL_AS void*)(Wg + rskip + k0),
                                         (LDS_AS void*)(BsW + 2048), 16, 0, 0);
        __syncthreads();            // compiler drains vmcnt(0) before barrier

        bf16x8 af[4], bfv[4];
#pragma unroll
        for (int tm = 0; tm < 4; ++tm) {
            int m = wm + tm * 16 + fr;
            af[tm] = *(const bf16x8*)&As[m * 32 + quad * 8];
        }
#pragma unroll
        for (int tn = 0; tn < 4; ++tn) {
            int n = wn + tn * 16 + fr;
            bfv[tn] = *(const bf16x8*)&Bs[n * 32 + quad * 8];
        }
#pragma unroll
        for (int tm = 0; tm < 4; ++tm)
#pragma unroll
            for (int tn = 0; tn < 4; ++tn)
                acc[tm][tn] = __builtin_amdgcn_mfma_f32_16x16x32_bf16(
                    af[tm], bfv[tn], acc[tm][tn], 0, 0, 0);
    }

    // epilogue: C/D layout col=lane&15, row=quad*4+reg (m89/m91-verified)
#pragma unroll
    for (int tm = 0; tm < 4; ++tm) {
#pragma unroll
        for (int tn = 0; tn < 4; ++tn) {
            const int col = bn + wn + tn * 16 + fr;
            const float bv = bias[col];
#pragma unroll
            for (int r = 0; r < 4; ++r) {
                const int row = bm + wm + tm * 16 + quad * 4 + r;
                stc(&C[(size_t)row * N + col], acc[tm][tn][r] + bv);
            }
        }
    }
}

// ---------------------------------------------------------------------------
// STP scan, chunked linear recurrence.
// state[i][j] <- R*state + (Gam/8)*v_i*k_j; y_i = sum_j (W+S)_ij q_j.
// 512 thr/block: thread (i=t>>3, jc=t&7) owns state row i, cols jc*8..+8,
// held as 4 x f32x2 so the backend emits v_pk_{mul,add,fma}_f32.
// 1024 blocks x 8 waves = 32 waves/CU (full occupancy).
// ---------------------------------------------------------------------------
__global__ __launch_bounds__(512) void stp_scan_local(
    const u16* __restrict__ qkv, const float* __restrict__ Lam,
    const float* __restrict__ Gam, float* __restrict__ F)
{
    const int c = blockIdx.x, h = blockIdx.y, b = blockIdx.z;
    const int t = threadIdx.x;
    const int i = t >> 3, jc = t & 7, j0 = jc << 3;
    const int hij = (h << 12) + (i << 6) + j0;

    f32x2 R2[4], Gv2[4], s2[4];
#pragma unroll
    for (int w = 0; w < 4; ++w) {
        R2[w].x  = 1.0f / (1.0f + expf(Lam[hij + 2 * w]));      // 1-sigmoid
        R2[w].y  = 1.0f / (1.0f + expf(Lam[hij + 2 * w + 1]));
        Gv2[w].x = Gam[hij + 2 * w]     * 0.125f;               // fold 1/sqrt(64)
        Gv2[w].y = Gam[hij + 2 * w + 1] * 0.125f;
        s2[w].x = 0.0f; s2[w].y = 0.0f;
    }

    const u16* rowp = qkv + (size_t)(b * L_ + c * TCHUNK) * TD;
    const int koff = D_ + (h << 6) + j0;
    const int voff = 2 * D_ + (h << 6) + i;

    for (int tt = 0; tt < TCHUNK; ++tt, rowp += TD) {
        const float v = bf2f(rowp[voff]);
        f32x2 vv; vv.x = v; vv.y = v;
        uint4 ku = *(const uint4*)(rowp + koff);
        uint32_t kw[4] = { ku.x, ku.y, ku.z, ku.w };
#pragma unroll
        for (int w = 0; w < 4; ++w) {
            f32x2 kf2 = bf2x2(kw[w]);
            s2[w] = R2[w] * s2[w] + (Gv2[w] * vv) * kf2;   // pk_fma + 2x pk_mul
        }
    }

    float* Fp = F + (((size_t)(b * H_ + h) * NCHUNK + c) << 12) + (i << 6) + j0;
    f32x4 o0; o0.x = s2[0].x; o0.y = s2[0].y; o0.z = s2[1].x; o0.w = s2[1].y;
    f32x4 o1; o1.x = s2[2].x; o1.y = s2[2].y; o1.z = s2[3].x; o1.w = s2[3].y;
    *(f32x4*)(Fp)     = o0;
    *(f32x4*)(Fp + 4) = o1;
}

// Sequential chunk combine per (b,h), in place: F[c] becomes Sinit[c]
// (state BEFORE chunk c). Sinit[c] = Rt ⊙ Sinit[c-1] + F[c-1], Rt = R^TCHUNK.
__global__ __launch_bounds__(256) void stp_combine(
    const float* __restrict__ Lam, float* __restrict__ F)
{
    const int h = blockIdx.x, b = blockIdx.y;
    const int t = threadIdx.x;
    const int i = t >> 2, jc = t & 3, j0 = jc << 4;
    const int hij = (h << 12) + (i << 6) + j0;

    float Rt[16], s[16];
#pragma unroll
    for (int j = 0; j < 16; ++j) {
        float R = 1.0f / (1.0f + expf(Lam[hij + j]));
        Rt[j] = powf(R, (float)TCHUNK);
        s[j] = 0.0f;
    }
    float* base = F + (((size_t)(b * H_ + h) * NCHUNK) << 12) + (i << 6) + j0;
    for (int c = 0; c < NCHUNK; ++c) {
        float* p = base + ((size_t)c << 12);
        float tmp[16];
#pragma unroll
        for (int j = 0; j < 16; ++j) tmp[j] = p[j];
#pragma unroll
        for (int j = 0; j < 16; ++j) { p[j] = s[j]; s[j] = fmaf(Rt[j], s[j], tmp[j]); }
    }
}

__global__ __launch_bounds__(512) void stp_scan_out(
    const u16* __restrict__ qkv, const float* __restrict__ Lam,
    const float* __restrict__ Gam, const float* __restrict__ Wst,
    const float* __restrict__ Sinit, u16* __restrict__ y)
{
    const int c = blockIdx.x, h = blockIdx.y, b = blockIdx.z;
    const int t = threadIdx.x;
    const int i = t >> 3, jc = t & 7, j0 = jc << 3;
    const int hij = (h << 12) + (i << 6) + j0;

    f32x2 R2[4], Gv2[4], Wr2[4], s2[4];
    const float* Sp = Sinit + (((size_t)(b * H_ + h) * NCHUNK + c) << 12) + (i << 6) + j0;
#pragma unroll
    for (int w = 0; w < 4; ++w) {
        R2[w].x  = 1.0f / (1.0f + expf(Lam[hij + 2 * w]));
        R2[w].y  = 1.0f / (1.0f + expf(Lam[hij + 2 * w + 1]));
        Gv2[w].x = Gam[hij + 2 * w]     * 0.125f;
        Gv2[w].y = Gam[hij + 2 * w + 1] * 0.125f;
        Wr2[w].x = Wst[hij + 2 * w];
        Wr2[w].y = Wst[hij + 2 * w + 1];
        s2[w].x  = Sp[2 * w];
        s2[w].y  = Sp[2 * w + 1];
    }

    const u16* rowp = qkv + (size_t)(b * L_ + c * TCHUNK) * TD;
    const int qoff = (h << 6) + j0;
    const int koff = D_ + qoff;
    const int voff = 2 * D_ + (h << 6) + i;
    u16* yp = y + (size_t)(b * L_ + c * TCHUNK) * D_ + (h << 6) + i;

    for (int tt = 0; tt < TCHUNK; ++tt, rowp += TD, yp += D_) {
        const float v = bf2f(rowp[voff]);
        f32x2 vv; vv.x = v; vv.y = v;
        uint4 qu = *(const uint4*)(rowp + qoff);
        uint4 ku = *(const uint4*)(rowp + koff);
        uint32_t qw[4] = { qu.x, qu.y, qu.z, qu.w };
        uint32_t kw[4] = { ku.x, ku.y, ku.z, ku.w };

        f32x2 ya2; ya2.x = 0.0f; ya2.y = 0.0f;
#pragma unroll
        for (int w = 0; w < 4; ++w) {
            f32x2 kf2 = bf2x2(kw[w]);
            f32x2 qf2 = bf2x2(qw[w]);
            s2[w] = R2[w] * s2[w] + (Gv2[w] * vv) * kf2;   // pk ops
            ya2   = (Wr2[w] + s2[w]) * qf2 + ya2;          // pk_add + pk_fma
        }
        float yacc = ya2.x + ya2.y;
        yacc += __shfl_xor(yacc, 1, 64);
        yacc += __shfl_xor(yacc, 2, 64);
        yacc += __shfl_xor(yacc, 4, 64);
        if (jc == 0) *yp = f2bf(yacc);
    }
}

__global__ void zero_out_f32(float* p, size_t n) {
    size_t i = (size_t)blockIdx.x * blockDim.x + threadIdx.x;
    if (i < n) p[i] = 0.0f;
}

// ---------------------------------------------------------------------------
extern "C" void kernel_launch(void* const* d_in, const int* in_sizes, int n_in,
                              void* d_out, int out_size, void* d_ws, size_t ws_size,
                              hipStream_t stream)
{
    const float* x      = (const float*)d_in[0];
    const float* Wqkv_w = (const float*)d_in[1];
    const float* Wqkv_b = (const float*)d_in[2];
    const float* out_w  = (const float*)d_in[3];
    const float* out_b  = (const float*)d_in[4];
    const float* Wst    = (const float*)d_in[5];
    const float* Lam    = (const float*)d_in[6];
    const float* Gam    = (const float*)d_in[7];
    float* out = (float*)d_out;                    // fp32 output

    // ws carve (151.0 MB, unchanged): qkv bf16 | y bf16 | F fp32.
    // Aliases (stream-order dead/live):
    //   xb (x as bf16, 33.5MB)   -> y region   (y written later by stp_scan_out)
    //   wqkvb (6.3MB)            -> F region   (F written later by stp_scan_local)
    //   outwb (2.1MB)            -> F region   (converted AFTER stp_scan_out)
    const size_t need = (size_t)B_ * L_ * TD * 2 + (size_t)B_ * L_ * D_ * 2
                      + (size_t)B_ * H_ * NCHUNK * 64 * 64 * 4;
    if (ws_size < need) {
        zero_out_f32<<<(out_size + 255) / 256, 256, 0, stream>>>(out, (size_t)out_size);
        return;
    }
    u16*   qkv = (u16*)d_ws;                                  // 50331648 elems
    u16*   y   = qkv + (size_t)B_ * L_ * TD;                  // 16777216 elems
    float* F   = (float*)(y + (size_t)B_ * L_ * D_);          //  4194304 floats
    u16*   xb    = y;                                         // alias, see above
    u16*   wqkvb = (u16*)F;                                   // alias
    u16*   outwb = (u16*)F;                                   // alias

    cvt_f32_bf16<<<(B_ * L_ * D_ / 8 + 255) / 256, 256, 0, stream>>>(
        x, xb, (size_t)B_ * L_ * D_ / 8);
    cvt_f32_bf16<<<(TD * D_ / 8 + 255) / 256, 256, 0, stream>>>(
        Wqkv_w, wqkvb, (size_t)TD * D_ / 8);
    gemm_bt_bias_bf16<u16><<<dim3(TD / 128, (B_ * L_) / 128), 256, 0, stream>>>(
        xb, wqkvb, Wqkv_b, qkv, B_ * L_, TD, D_);
    stp_scan_local<<<dim3(NCHUNK, H_, B_), 512, 0, stream>>>(qkv, Lam, Gam, F);
    stp_combine<<<dim3(H_, B_), 256, 0, stream>>>(Lam, F);
    stp_scan_out<<<dim3(NCHUNK, H_, B_), 512, 0, stream>>>(qkv, Lam, Gam, Wst, F, y);
    cvt_f32_bf16<<<(D_ * D_ / 8 + 255) / 256, 256, 0, stream>>>(
        out_w, outwb, (size_t)D_ * D_ / 8);
    gemm_bt_bias_bf16<float><<<dim3(D_ / 128, (B_ * L_) / 128), 256, 0, stream>>>(
        y, outwb, out_b, out, B_ * L_, D_, D_);
}

// Round 3
// 670.107 us; speedup vs baseline: 1.1185x; 1.1185x over previous
//
#include <hip/hip_runtime.h>
#include <stdint.h>

typedef unsigned short u16;
typedef __bf16 bf16x8 __attribute__((ext_vector_type(8)));
typedef float  f32x4  __attribute__((ext_vector_type(4)));

#define GLOBAL_AS __attribute__((address_space(1)))
#define LDS_AS    __attribute__((address_space(3)))

#define B_ 4
#define L_ 4096
#define D_ 1024
#define H_ 16
#define TD 3072         // 3*D
#define NCHUNK 16
#define TCHUNK 256      // L_/NCHUNK

__device__ __forceinline__ float bf2f(u16 h) {
    union { uint32_t u; float f; } v; v.u = ((uint32_t)h) << 16; return v.f;
}
__device__ __forceinline__ u16 f2bf(float f) {
    union { float f; uint32_t u; } v; v.f = f;
    uint32_t u = v.u;
    u += 0x7fffu + ((u >> 16) & 1u);   // round-to-nearest-even
    return (u16)(u >> 16);
}
__device__ __forceinline__ void unp8(uint4 u, float* f) {
    f[0] = bf2f((u16)(u.x)); f[1] = bf2f((u16)(u.x >> 16));
    f[2] = bf2f((u16)(u.y)); f[3] = bf2f((u16)(u.y >> 16));
    f[4] = bf2f((u16)(u.z)); f[5] = bf2f((u16)(u.z >> 16));
    f[6] = bf2f((u16)(u.w)); f[7] = bf2f((u16)(u.w >> 16));
}

// pack 8 contiguous fp32 into 8 bf16 (RTE)
__device__ __forceinline__ uint4 ld8f(const float* p) {
    const float4 a = *(const float4*)p;
    const float4 b = *(const float4*)(p + 4);
    uint4 r;
    r.x = (uint32_t)f2bf(a.x) | ((uint32_t)f2bf(a.y) << 16);
    r.y = (uint32_t)f2bf(a.z) | ((uint32_t)f2bf(a.w) << 16);
    r.z = (uint32_t)f2bf(b.x) | ((uint32_t)f2bf(b.y) << 16);
    r.w = (uint32_t)f2bf(b.z) | ((uint32_t)f2bf(b.w) << 16);
    return r;
}

// store helper: C is bf16 (qkv intermediate) or fp32 (final output)
__device__ __forceinline__ void stc(u16* p, float v)   { *p = f2bf(v); }
__device__ __forceinline__ void stc(float* p, float v) { *p = v; }

// fp32 -> bf16 bulk convert, 8 elems/thread
__global__ __launch_bounds__(256) void cvt_f32_bf16(
    const float* __restrict__ in, u16* __restrict__ out, size_t n8)
{
    size_t i = (size_t)blockIdx.x * 256 + threadIdx.x;
    if (i >= n8) return;
    *(uint4*)(out + i * 8) = ld8f(in + i * 8);
}

// ---------------------------------------------------------------------------
// NT GEMM (m97 structure): C(M,N) = A(M,K)bf16 @ W(N,K)bf16^T + bias(fp32).
// 128x128 tile, BK=32, 256 thr (4 waves), 4x4 16x16x32 MFMA per wave.
// Staging via global_load_lds width=16 into LINEAR LDS [128][32].
// ---------------------------------------------------------------------------
template <typename TC>
__global__ __launch_bounds__(256) void gemm_bt_bias_bf16(
    const u16* __restrict__ A, const u16* __restrict__ W,
    const float* __restrict__ bias, TC* __restrict__ C,
    int M, int N, int K)
{
    __shared__ u16 As[128 * 32];
    __shared__ u16 Bs[128 * 32];

    const int tid  = threadIdx.x;
    const int lane = tid & 63;
    const int wid  = tid >> 6;
    const int bm = blockIdx.y * 128;
    const int bn = blockIdx.x * 128;

    const int wm = (wid & 1) * 64;
    const int wn = (wid >> 1) * 64;
    const int fr   = lane & 15;
    const int quad = lane >> 4;

    const u16* Ag = A + (size_t)(bm + (tid >> 2)) * K + (tid & 3) * 8;
    const u16* Wg = W + (size_t)(bn + (tid >> 2)) * K + (tid & 3) * 8;
    const size_t rskip = (size_t)64 * K;

    u16* AsW = As + wid * 512;      // wave-uniform LDS base, round 0
    u16* BsW = Bs + wid * 512;

    f32x4 acc[4][4] = {};

    for (int k0 = 0; k0 < K; k0 += 32) {
        __syncthreads();            // all waves done reading previous tile
        __builtin_amdgcn_global_load_lds((const GLOBAL_AS void*)(Ag + k0),
                                         (LDS_AS void*)(AsW),        16, 0, 0);
        __builtin_amdgcn_global_load_lds((const GLOBAL_AS void*)(Ag + rskip + k0),
                                         (LDS_AS void*)(AsW + 2048), 16, 0, 0);
        __builtin_amdgcn_global_load_lds((const GLOBAL_AS void*)(Wg + k0),
                                         (LDS_AS void*)(BsW),        16, 0, 0);
        __builtin_amdgcn_global_load_lds((const GLOBAL_AS void*)(Wg + rskip + k0),
                                         (LDS_AS void*)(BsW + 2048), 16, 0, 0);
        __syncthreads();            // compiler drains vmcnt(0) before barrier

        bf16x8 af[4], bfv[4];
#pragma unroll
        for (int tm = 0; tm < 4; ++tm) {
            int m = wm + tm * 16 + fr;
            af[tm] = *(const bf16x8*)&As[m * 32 + quad * 8];
        }
#pragma unroll
        for (int tn = 0; tn < 4; ++tn) {
            int n = wn + tn * 16 + fr;
            bfv[tn] = *(const bf16x8*)&Bs[n * 32 + quad * 8];
        }
#pragma unroll
        for (int tm = 0; tm < 4; ++tm)
#pragma unroll
            for (int tn = 0; tn < 4; ++tn)
                acc[tm][tn] = __builtin_amdgcn_mfma_f32_16x16x32_bf16(
                    af[tm], bfv[tn], acc[tm][tn], 0, 0, 0);
    }

    // epilogue: C/D layout col=lane&15, row=quad*4+reg (m89/m91-verified)
#pragma unroll
    for (int tm = 0; tm < 4; ++tm) {
#pragma unroll
        for (int tn = 0; tn < 4; ++tn) {
            const int col = bn + wn + tn * 16 + fr;
            const float bv = bias[col];
#pragma unroll
            for (int r = 0; r < 4; ++r) {
                const int row = bm + wm + tm * 16 + quad * 4 + r;
                stc(&C[(size_t)row * N + col], acc[tm][tn][r] + bv);
            }
        }
    }
}

// ---------------------------------------------------------------------------
// STP scan kernels. Thread mapping: 256 thr/block, thread owns 2 i-rows x 8 j
// (ig = t>>3 -> i0 = 2*ig; jc = t&7 -> j0 = 8*jc). Amortizes q/k unpack over
// 2 rows; register prefetch of next timestep breaks the load->use chain.
// __launch_bounds__(256,4): cap 128 VGPR -> 4 blocks/CU (full 1024-block
// residency at 16 waves/CU).
// ---------------------------------------------------------------------------
__global__ __launch_bounds__(256, 4) void stp_scan_local(
    const u16* __restrict__ qkv, const float* __restrict__ Lam,
    const float* __restrict__ Gam, float* __restrict__ F)
{
    const int c = blockIdx.x, h = blockIdx.y, b = blockIdx.z;
    const int t = threadIdx.x;
    const int ig = t >> 3, jc = t & 7;
    const int i0 = ig << 1, j0 = jc << 3;
    const int hij = (h << 12) + (i0 << 6) + j0;   // row i0; row i0+1 at +64

    float R[2][8], Gv[2][8], s[2][8];
#pragma unroll
    for (int r = 0; r < 2; ++r)
#pragma unroll
        for (int j = 0; j < 8; ++j) {
            R[r][j]  = 1.0f / (1.0f + expf(Lam[hij + r * 64 + j]));  // 1-sigmoid
            Gv[r][j] = Gam[hij + r * 64 + j] * 0.125f;               // fold 1/sqrt(64)
            s[r][j]  = 0.0f;
        }

    const u16* rowp = qkv + (size_t)(b * L_ + c * TCHUNK) * TD;
    const int koff = D_ + (h << 6) + j0;
    const int voff = 2 * D_ + (h << 6) + i0;

    uint4    ku = *(const uint4*)(rowp + koff);
    uint32_t vu = *(const uint32_t*)(rowp + voff);

    for (int tt = 0; tt < TCHUNK; ++tt) {
        // prefetch next row (last iter overreads <=16B into adjacent ws region)
        uint4    kn = *(const uint4*)(rowp + TD + koff);
        uint32_t vn = *(const uint32_t*)(rowp + TD + voff);

        float kf[8];
        unp8(ku, kf);
        const float v0 = bf2f((u16)vu);
        const float v1 = bf2f((u16)(vu >> 16));
#pragma unroll
        for (int j = 0; j < 8; ++j) {
            s[0][j] = fmaf(R[0][j], s[0][j], (Gv[0][j] * v0) * kf[j]);
            s[1][j] = fmaf(R[1][j], s[1][j], (Gv[1][j] * v1) * kf[j]);
        }
        ku = kn; vu = vn; rowp += TD;
    }

    float* Fp = F + (((size_t)(b * H_ + h) * NCHUNK + c) << 12) + (i0 << 6) + j0;
#pragma unroll
    for (int r = 0; r < 2; ++r) {
        *(f32x4*)(Fp + r * 64)     = *(const f32x4*)(&s[r][0]);
        *(f32x4*)(Fp + r * 64 + 4) = *(const f32x4*)(&s[r][4]);
    }
}

// Sequential chunk combine per (b,h), in place: F[c] becomes Sinit[c]
// (state BEFORE chunk c). Sinit[c] = Rt ⊙ Sinit[c-1] + F[c-1], Rt = R^TCHUNK.
__global__ __launch_bounds__(256) void stp_combine(
    const float* __restrict__ Lam, float* __restrict__ F)
{
    const int h = blockIdx.x, b = blockIdx.y;
    const int t = threadIdx.x;
    const int i = t >> 2, jc = t & 3, j0 = jc << 4;
    const int hij = (h << 12) + (i << 6) + j0;

    float Rt[16], s[16];
#pragma unroll
    for (int j = 0; j < 16; ++j) {
        float R = 1.0f / (1.0f + expf(Lam[hij + j]));
        Rt[j] = powf(R, (float)TCHUNK);
        s[j] = 0.0f;
    }
    float* base = F + (((size_t)(b * H_ + h) * NCHUNK) << 12) + (i << 6) + j0;
    for (int c = 0; c < NCHUNK; ++c) {
        float* p = base + ((size_t)c << 12);
        float tmp[16];
#pragma unroll
        for (int j = 0; j < 16; ++j) tmp[j] = p[j];
#pragma unroll
        for (int j = 0; j < 16; ++j) { p[j] = s[j]; s[j] = fmaf(Rt[j], s[j], tmp[j]); }
    }
}

// y_t = (W + S_t) q_t computed via folded state s~ = S + W:
//   s~ = fma(R, s~, C + Gv*v*k),  C = W*(1-R)   (exact algebra)
// -> 4 VALU ops per state element per step (mul, fma, fma, + y fma).
__global__ __launch_bounds__(256, 4) void stp_scan_out(
    const u16* __restrict__ qkv, const float* __restrict__ Lam,
    const float* __restrict__ Gam, const float* __restrict__ Wst,
    const float* __restrict__ Sinit, u16* __restrict__ y)
{
    const int c = blockIdx.x, h = blockIdx.y, b = blockIdx.z;
    const int t = threadIdx.x;
    const int ig = t >> 3, jc = t & 7;
    const int i0 = ig << 1, j0 = jc << 3;
    const int hij = (h << 12) + (i0 << 6) + j0;

    float R[2][8], Gv[2][8], Cc[2][8], s[2][8];
    const float* Sp = Sinit + (((size_t)(b * H_ + h) * NCHUNK + c) << 12) + (i0 << 6) + j0;
#pragma unroll
    for (int r = 0; r < 2; ++r)
#pragma unroll
        for (int j = 0; j < 8; ++j) {
            const float Rv = 1.0f / (1.0f + expf(Lam[hij + r * 64 + j]));
            const float Wv = Wst[hij + r * 64 + j];
            R[r][j]  = Rv;
            Gv[r][j] = Gam[hij + r * 64 + j] * 0.125f;
            Cc[r][j] = Wv * (1.0f - Rv);
            s[r][j]  = Sp[r * 64 + j] + Wv;       // folded state s~ = S + W
        }

    const u16* rowp = qkv + (size_t)(b * L_ + c * TCHUNK) * TD;
    const int qoff = (h << 6) + j0;
    const int koff = D_ + qoff;
    const int voff = 2 * D_ + (h << 6) + i0;
    u16* yp = y + (size_t)(b * L_ + c * TCHUNK) * D_ + (h << 6) + i0;

    uint4    qu = *(const uint4*)(rowp + qoff);
    uint4    ku = *(const uint4*)(rowp + koff);
    uint32_t vu = *(const uint32_t*)(rowp + voff);

    for (int tt = 0; tt < TCHUNK; ++tt) {
        // prefetch next row (last iter overreads <=16B into adjacent ws region)
        uint4    qn = *(const uint4*)(rowp + TD + qoff);
        uint4    kn = *(const uint4*)(rowp + TD + koff);
        uint32_t vn = *(const uint32_t*)(rowp + TD + voff);

        float qf[8], kf[8];
        unp8(qu, qf); unp8(ku, kf);
        const float v0 = bf2f((u16)vu);
        const float v1 = bf2f((u16)(vu >> 16));

        float ya0 = 0.0f, ya1 = 0.0f;
#pragma unroll
        for (int j = 0; j < 8; ++j) {
            s[0][j] = fmaf(R[0][j], s[0][j], fmaf(Gv[0][j] * v0, kf[j], Cc[0][j]));
            ya0 = fmaf(s[0][j], qf[j], ya0);
            s[1][j] = fmaf(R[1][j], s[1][j], fmaf(Gv[1][j] * v1, kf[j], Cc[1][j]));
            ya1 = fmaf(s[1][j], qf[j], ya1);
        }
        ya0 += __shfl_xor(ya0, 1, 64);
        ya0 += __shfl_xor(ya0, 2, 64);
        ya0 += __shfl_xor(ya0, 4, 64);
        ya1 += __shfl_xor(ya1, 1, 64);
        ya1 += __shfl_xor(ya1, 2, 64);
        ya1 += __shfl_xor(ya1, 4, 64);
        if (jc == 0) {
            uint32_t pk = (uint32_t)f2bf(ya0) | ((uint32_t)f2bf(ya1) << 16);
            *(uint32_t*)yp = pk;                  // rows i0,i0+1 adjacent in y
        }
        qu = qn; ku = kn; vu = vn;
        rowp += TD; yp += D_;
    }
}

__global__ void zero_out_f32(float* p, size_t n) {
    size_t i = (size_t)blockIdx.x * blockDim.x + threadIdx.x;
    if (i < n) p[i] = 0.0f;
}

// ---------------------------------------------------------------------------
extern "C" void kernel_launch(void* const* d_in, const int* in_sizes, int n_in,
                              void* d_out, int out_size, void* d_ws, size_t ws_size,
                              hipStream_t stream)
{
    const float* x      = (const float*)d_in[0];
    const float* Wqkv_w = (const float*)d_in[1];
    const float* Wqkv_b = (const float*)d_in[2];
    const float* out_w  = (const float*)d_in[3];
    const float* out_b  = (const float*)d_in[4];
    const float* Wst    = (const float*)d_in[5];
    const float* Lam    = (const float*)d_in[6];
    const float* Gam    = (const float*)d_in[7];
    float* out = (float*)d_out;                    // fp32 output

    // ws carve (151.0 MB, unchanged): qkv bf16 | y bf16 | F fp32.
    // Aliases (stream-order dead/live):
    //   xb (x as bf16, 33.5MB)   -> y region   (y written later by stp_scan_out)
    //   wqkvb (6.3MB)            -> F region   (F written later by stp_scan_local)
    //   outwb (2.1MB)            -> F region   (converted AFTER stp_scan_out)
    const size_t need = (size_t)B_ * L_ * TD * 2 + (size_t)B_ * L_ * D_ * 2
                      + (size_t)B_ * H_ * NCHUNK * 64 * 64 * 4;
    if (ws_size < need) {
        zero_out_f32<<<(out_size + 255) / 256, 256, 0, stream>>>(out, (size_t)out_size);
        return;
    }
    u16*   qkv = (u16*)d_ws;                                  // 50331648 elems
    u16*   y   = qkv + (size_t)B_ * L_ * TD;                  // 16777216 elems
    float* F   = (float*)(y + (size_t)B_ * L_ * D_);          //  4194304 floats
    u16*   xb    = y;                                         // alias, see above
    u16*   wqkvb = (u16*)F;                                   // alias
    u16*   outwb = (u16*)F;                                   // alias

    cvt_f32_bf16<<<(B_ * L_ * D_ / 8 + 255) / 256, 256, 0, stream>>>(
        x, xb, (size_t)B_ * L_ * D_ / 8);
    cvt_f32_bf16<<<(TD * D_ / 8 + 255) / 256, 256, 0, stream>>>(
        Wqkv_w, wqkvb, (size_t)TD * D_ / 8);
    gemm_bt_bias_bf16<u16><<<dim3(TD / 128, (B_ * L_) / 128), 256, 0, stream>>>(
        xb, wqkvb, Wqkv_b, qkv, B_ * L_, TD, D_);
    stp_scan_local<<<dim3(NCHUNK, H_, B_), 256, 0, stream>>>(qkv, Lam, Gam, F);
    stp_combine<<<dim3(H_, B_), 256, 0, stream>>>(Lam, F);
    stp_scan_out<<<dim3(NCHUNK, H_, B_), 256, 0, stream>>>(qkv, Lam, Gam, Wst, F, y);
    cvt_f32_bf16<<<(D_ * D_ / 8 + 255) / 256, 256, 0, stream>>>(
        out_w, outwb, (size_t)D_ * D_ / 8);
    gemm_bt_bias_bf16<float><<<dim3(D_ / 128, (B_ * L_) / 128), 256, 0, stream>>>(
        y, outwb, out_b, out, B_ * L_, D_, D_);
}